// Round 1
// baseline (301.106 us; speedup 1.0000x reference)
//
#include <hip/hip_runtime.h>
#include <hip/hip_bf16.h>

// Conv2D 3x3, stride 1, pad 1: x[8,16,512,512] f32, w[16,16*9] f32 -> out[8,16,512,512] f32
//
// Strategy (round 0 baseline, fp32 vector-ALU):
//  - tile: 64(W) x 16(H) outputs per block, 256 threads, 4 consecutive W-pixels/thread
//  - all 16 out-channels accumulated in registers (64 acc VGPRs)
//  - weights read with wave-uniform indices -> scalar loads (constant cache)
//  - input sliding window: 3 rows x 6 cols in registers per in-channel; interior
//    float4 load is always w-in-bounds (w0 multiple of 4), halo cols scalar+predicated
//  - fp32 FMA floor at 157.3 TF = 61.5 us; HBM floor ~43 us

#define IH 512
#define IW 512
#define CI 16
#define CO 16

__global__ __launch_bounds__(256, 4)
void conv3x3_f32(const float* __restrict__ x, const float* __restrict__ wgt,
                 float* __restrict__ out) {
    const int t   = threadIdx.x;
    const int w0l = (t & 15) * 4;          // 0..60 within tile
    const int hl  = t >> 4;                // 0..15 within tile
    const int wb  = blockIdx.x * 64 + w0l; // global w of first pixel
    const int h   = blockIdx.y * 16 + hl;  // global h
    const int n   = blockIdx.z;

    float acc[CO][4];
#pragma unroll
    for (int co = 0; co < CO; ++co)
#pragma unroll
        for (int p = 0; p < 4; ++p) acc[co][p] = 0.0f;

    const float* xn = x + (size_t)n * CI * IH * IW;

    for (int ci = 0; ci < CI; ++ci) {
        const float* xc = xn + (size_t)ci * IH * IW;

        // 3 rows x 6 cols window: cols wb-1 .. wb+4
        float r[3][6];
#pragma unroll
        for (int rr = 0; rr < 3; ++rr) {
            const int hh = h + rr - 1;
            if (hh >= 0 && hh < IH) {
                const float* p = xc + (size_t)hh * IW + wb;
                const float4 m = *(const float4*)p;     // aligned, always in-bounds in w
                r[rr][0] = (wb > 0)       ? p[-1] : 0.0f;
                r[rr][1] = m.x; r[rr][2] = m.y; r[rr][3] = m.z; r[rr][4] = m.w;
                r[rr][5] = (wb + 4 < IW)  ? p[4]  : 0.0f;
            } else {
#pragma unroll
                for (int j = 0; j < 6; ++j) r[rr][j] = 0.0f;
            }
        }

#pragma unroll
        for (int kh = 0; kh < 3; ++kh) {
#pragma unroll
            for (int kw = 0; kw < 3; ++kw) {
#pragma unroll
                for (int co = 0; co < CO; ++co) {
                    // uniform address -> s_load (scalar pipe, constant cache)
                    const float wv = wgt[co * (CI * 9) + ci * 9 + kh * 3 + kw];
#pragma unroll
                    for (int p = 0; p < 4; ++p)
                        acc[co][p] = fmaf(r[kh][kw + p], wv, acc[co][p]);
                }
            }
        }
    }

    float* on = out + (size_t)n * CO * IH * IW + (size_t)h * IW + wb;
#pragma unroll
    for (int co = 0; co < CO; ++co) {
        float4 v;
        v.x = acc[co][0]; v.y = acc[co][1]; v.z = acc[co][2]; v.w = acc[co][3];
        *(float4*)(on + (size_t)co * IH * IW) = v;
    }
}

extern "C" void kernel_launch(void* const* d_in, const int* in_sizes, int n_in,
                              void* d_out, int out_size, void* d_ws, size_t ws_size,
                              hipStream_t stream) {
    const float* x = (const float*)d_in[0];
    const float* w = (const float*)d_in[1];
    float* out     = (float*)d_out;

    dim3 grid(IW / 64, IH / 16, 8);   // 8 x 32 x 8 = 2048 blocks
    dim3 block(256);
    conv3x3_f32<<<grid, block, 0, stream>>>(x, w, out);
}